// Round 2
// baseline (4779.232 us; speedup 1.0000x reference)
//
#include <hip/hip_runtime.h>
#include <hip/hip_bf16.h>

#define N_NODES 20000
#define N_EDGES 600000
#define HEADS 4
#define NPAD 20032

// packed bf16 weight offsets (elements), all rows are K=128
#define WOFF_WEH  0        // [512][128]  aW_w[h][d][256:384], rows h*128+d
#define WOFF_WM1  65536    // [128][128]  nw1[j][256:384]
#define WOFF_NW2  81920    // [128][128]
#define WOFF_NW3  98304    // [128][128]
#define WOFF_WE1  114688   // [128][128]  ew1[j][256:384]
#define WOFF_EW2  131072   // [128][128]
#define WOFF_EW3  147456   // [128][128]
#define WOFF_WN   163840   // [1280][128] node-proj: heads-src 512 | heads-snk 512 | msg1-src 128 | msg1-snk 128
#define WOFF_WX   327680   // [256][128]  x-proj: ew1-src 128 | ew1-snk 128
#define WPACK2    360448

typedef __attribute__((ext_vector_type(8))) short s16x8;
typedef __attribute__((ext_vector_type(4))) float f32x4;
typedef unsigned int u32;
typedef unsigned short u16;

__device__ __forceinline__ float bf2f(u16 h){ return __uint_as_float(((u32)h)<<16); }
__device__ __forceinline__ u16 f2bf(float f){
  u32 u = __float_as_uint(f);
  u32 r = u + 0x7FFFu + ((u>>16)&1u);
  return (u16)(r>>16);
}
__device__ __forceinline__ float gelu_f(float x){ return 0.5f*x*(1.0f+erff(x*0.70710678118654752f)); }
__device__ __forceinline__ u32 fkey(float f){ u32 u = __float_as_uint(f); return (u & 0x80000000u) ? ~u : (u | 0x80000000u); }
__device__ __forceinline__ float fdec(u32 k){ return (k & 0x80000000u) ? __uint_as_float(k & 0x7FFFFFFFu) : __uint_as_float(~k); }

// ---------------- pack weights + bb to bf16 ----------------
__global__ __launch_bounds__(256) void k_pack(
    const float* __restrict__ aW, const float* __restrict__ nw1, const float* __restrict__ nw2,
    const float* __restrict__ nw3, const float* __restrict__ ew1, const float* __restrict__ ew2,
    const float* __restrict__ ew3, const float* __restrict__ bb,
    u16* __restrict__ wpk, u16* __restrict__ bbp)
{
  int i = blockIdx.x*256 + threadIdx.x;
  if (i < WPACK2){
    float v; int k = i & 127;
    if (i < WOFF_WM1){ int r = i>>7; int h=r>>7, d=r&127; v = aW[h*49152 + d*384 + 256 + k]; }
    else if (i < WOFF_NW2){ int j = (i-WOFF_WM1)>>7; v = nw1[j*384 + 256 + k]; }
    else if (i < WOFF_NW3){ v = nw2[i-WOFF_NW2]; }
    else if (i < WOFF_WE1){ v = nw3[i-WOFF_NW3]; }
    else if (i < WOFF_EW2){ int j = (i-WOFF_WE1)>>7; v = ew1[j*384 + 256 + k]; }
    else if (i < WOFF_EW3){ v = ew2[i-WOFF_EW2]; }
    else if (i < WOFF_WN) { v = ew3[i-WOFF_EW3]; }
    else if (i < WOFF_WX){
      int r = (i-WOFF_WN)>>7;
      if (r < 512){ int h=r>>7, d=r&127; v = aW[h*49152 + d*384 + k]; }
      else if (r < 1024){ int r2=r-512; int h=r2>>7, d=r2&127; v = aW[h*49152 + d*384 + 128 + k]; }
      else if (r < 1152){ v = nw1[(r-1024)*384 + k]; }
      else { v = nw1[(r-1152)*384 + 128 + k]; }
    } else {
      int r = (i-WOFF_WX)>>7;
      v = (r < 128) ? ew1[r*384 + k] : ew1[(r-128)*384 + 128 + k];
    }
    wpk[i] = f2bf(v);
  }
  if (i < N_NODES*128) bbp[i] = f2bf(bb[i]);
}

__global__ __launch_bounds__(256) void k_init(u32* __restrict__ smax, float* __restrict__ norm, u32* __restrict__ cnt)
{
  int i = blockIdx.x*256 + threadIdx.x;
  if (i < N_NODES*HEADS){ smax[i] = 0x007FFFFFu; norm[i] = 0.f; }
  if (i < N_NODES) cnt[i] = 0u;
}

// ---------------- shared GEMM helpers (A in LDS [64][128] bf16 swizzled) ----------------
template<int NT>
__device__ __forceinline__ void gemmK128(const char* ab, const u16* __restrict__ wb,
                                         int n0, int l15, int lg, f32x4 (&acc)[4][NT])
{
  const int swz = (l15&7)<<4;
  #pragma unroll
  for (int ks=0; ks<4; ++ks){
    s16x8 af[4];
    #pragma unroll
    for (int mt=0;mt<4;++mt)
      af[mt] = *(const s16x8*)(ab + (mt*16+l15)*256 + (((ks*4+lg)*16) ^ swz));
    #pragma unroll
    for (int nt=0;nt<NT;++nt){
      s16x8 bf = *(const s16x8*)(wb + (size_t)(n0+nt*16+l15)*128 + ks*32 + lg*8);
      #pragma unroll
      for (int mt=0;mt<4;++mt)
        acc[mt][nt] = __builtin_amdgcn_mfma_f32_16x16x32_bf16(af[mt], bf, acc[mt][nt], 0,0,0);
    }
  }
}

__device__ __forceinline__ void stage_ea(char* eab, const float* __restrict__ eattr, int e0, int t)
{
  const int row = t>>2, q = t&3;
  const float* er = eattr + (size_t)(e0+row)*128 + q*32;
  const int swz = (row&7)<<4;
  #pragma unroll
  for (int c=0;c<4;++c){
    float4 x0 = ((const float4*)er)[c*2];
    float4 x1 = ((const float4*)er)[c*2+1];
    int4 v;
    v.x = (int)((u32)f2bf(x0.x) | ((u32)f2bf(x0.y)<<16));
    v.y = (int)((u32)f2bf(x0.z) | ((u32)f2bf(x0.w)<<16));
    v.z = (int)((u32)f2bf(x1.x) | ((u32)f2bf(x1.y)<<16));
    v.w = (int)((u32)f2bf(x1.z) | ((u32)f2bf(x1.w)<<16));
    *(int4*)(eab + row*256 + ((q*64 + c*16) ^ swz)) = v;
  }
}

// ---------------- node projection tables ----------------
__global__ __launch_bounds__(256) void k_nproj(const u16* __restrict__ bbp, const u16* __restrict__ wpk,
                                               u16* __restrict__ Pn)
{
  __shared__ u16 a[64*128];
  char* ab = (char*)a;
  const int t = threadIdx.x, w = t>>6, l = t&63, l15 = l&15, lg = l>>4;
  const int nbase = blockIdx.x*64;
  {
    int row = t>>2, q = t&3;
    int gr = nbase+row; if (gr >= N_NODES) gr = N_NODES-1;
    const int4* srow = (const int4*)(bbp + (size_t)gr*128 + q*32);
    const int swz = (row&7)<<4;
    #pragma unroll
    for (int c=0;c<4;++c){
      int4 v = srow[c];
      *(int4*)(ab + row*256 + ((q*64 + c*16) ^ swz)) = v;
    }
  }
  __syncthreads();
  const u16* wn = wpk + WOFF_WN;
  for (int cb=0; cb<5; ++cb){
    int n0 = (cb*4 + w)*64;
    f32x4 acc[4][4];
    #pragma unroll
    for (int mt=0;mt<4;++mt){
      #pragma unroll
      for (int nt=0;nt<4;++nt){ f32x4 z={0.f,0.f,0.f,0.f}; acc[mt][nt]=z; }
    }
    gemmK128<4>(ab, wn, n0, l15, lg, acc);
    #pragma unroll
    for (int nt=0;nt<4;++nt){
      int col = n0 + nt*16 + l15;
      #pragma unroll
      for (int mt=0;mt<4;++mt){
        #pragma unroll
        for (int r=0;r<4;++r){
          int row = mt*16 + lg*4 + r;
          Pn[(size_t)(nbase+row)*1280 + col] = f2bf(acc[mt][nt][r]);
        }
      }
    }
  }
}

__global__ __launch_bounds__(256) void k_xproj(const u16* __restrict__ xbp, const u16* __restrict__ wpk,
                                               u16* __restrict__ Xp)
{
  __shared__ u16 a[64*128];
  char* ab = (char*)a;
  const int t = threadIdx.x, w = t>>6, l = t&63, l15 = l&15, lg = l>>4;
  const int nbase = blockIdx.x*64;
  {
    int row = t>>2, q = t&3;
    int gr = nbase+row; if (gr >= N_NODES) gr = N_NODES-1;
    const int4* srow = (const int4*)(xbp + (size_t)gr*128 + q*32);
    const int swz = (row&7)<<4;
    #pragma unroll
    for (int c=0;c<4;++c){
      int4 v = srow[c];
      *(int4*)(ab + row*256 + ((q*64 + c*16) ^ swz)) = v;
    }
  }
  __syncthreads();
  const u16* wx = wpk + WOFF_WX;
  int n0 = w*64;
  f32x4 acc[4][4];
  #pragma unroll
  for (int mt=0;mt<4;++mt){
    #pragma unroll
    for (int nt=0;nt<4;++nt){ f32x4 z={0.f,0.f,0.f,0.f}; acc[mt][nt]=z; }
  }
  gemmK128<4>(ab, wx, n0, l15, lg, acc);
  #pragma unroll
  for (int nt=0;nt<4;++nt){
    int col = n0 + nt*16 + l15;
    #pragma unroll
    for (int mt=0;mt<4;++mt){
      #pragma unroll
      for (int r=0;r<4;++r){
        int row = mt*16 + lg*4 + r;
        Xp[(size_t)(nbase+row)*256 + col] = f2bf(acc[mt][nt][r]);
      }
    }
  }
}

// ---------------- edge pass A: logits + segment-max + msg MLP ----------------
__global__ __launch_bounds__(256,3) void k_edgeA(
  const float* __restrict__ eattr, const int* __restrict__ eidx,
  const u16* __restrict__ wpk, const u16* __restrict__ Pn,
  const float* __restrict__ aW_b, const float* __restrict__ aA_w, const float* __restrict__ aA_b,
  const float* __restrict__ nb1, const float* __restrict__ nb2, const float* __restrict__ nb3,
  float* __restrict__ logits, u32* __restrict__ smax, u32* __restrict__ cnt,
  u16* __restrict__ msg)
{
  __shared__ u16 ea[64*128];
  __shared__ u16 ms[64*128];
  __shared__ u16 pp[64*128];
  __shared__ int sof[64], kof[64], snkid[64];
  char* eab=(char*)ea; char* msb=(char*)ms; char* ppb=(char*)pp;
  const char* PnB = (const char*)Pn;
  const int t = threadIdx.x;
  const int e0 = blockIdx.x*64;
  const int w = t>>6, l = t&63, l15 = l&15, lg = l>>4;

  stage_ea(eab, eattr, e0, t);
  if (t < 64){
    int s = eidx[e0+t], k = eidx[N_EDGES + e0 + t];
    sof[t] = s*2560; kof[t] = k*2560;   // byte offsets into Pn rows
    snkid[t] = k;
    atomicAdd(&cnt[k], 1u);
  }
  __syncthreads();

  // ---- logits: wave w = head w, no barrier needed ----
  {
    const u16* wb = wpk + WOFF_WEH + w*(128*128);
    float lp[4][4];
    #pragma unroll
    for (int a=0;a<4;++a){
      #pragma unroll
      for (int b=0;b<4;++b) lp[a][b]=0.f;
    }
    #pragma unroll
    for (int nh=0; nh<2; ++nh){
      f32x4 acc[4][4];
      #pragma unroll
      for (int mt=0;mt<4;++mt){
        #pragma unroll
        for (int nt=0;nt<4;++nt){ f32x4 z={0.f,0.f,0.f,0.f}; acc[mt][nt]=z; }
      }
      gemmK128<4>(eab, wb, nh*64, l15, lg, acc);
      #pragma unroll
      for (int nt=0;nt<4;++nt){
        int col = nh*64 + nt*16 + l15;
        float bia = aW_b[w*128 + col];
        float avw = aA_w[w*128 + col];
        int cs = (w*128 + col)*2;
        int ck = (512 + w*128 + col)*2;
        #pragma unroll
        for (int mt=0;mt<4;++mt){
          #pragma unroll
          for (int r=0;r<4;++r){
            int row = mt*16 + lg*4 + r;
            float g = bf2f(*(const u16*)(PnB + sof[row] + cs))
                    + bf2f(*(const u16*)(PnB + kof[row] + ck));
            float v = acc[mt][nt][r] + bia + g;
            v = (v>0.f) ? v : 0.2f*v;
            lp[mt][r] += v*avw;
          }
        }
      }
    }
    float ab_ = aA_b[w];
    #pragma unroll
    for (int mt=0;mt<4;++mt){
      #pragma unroll
      for (int r=0;r<4;++r){
        float v = lp[mt][r];
        v += __shfl_xor(v,1);
        v += __shfl_xor(v,2);
        v += __shfl_xor(v,4);
        v += __shfl_xor(v,8);
        if (l15==0){
          int row = mt*16 + lg*4 + r;
          int e = e0 + row;
          float lgt = v + ab_;
          logits[e*HEADS + w] = lgt;
          atomicMax(&smax[snkid[row]*HEADS + w], fkey(lgt));
        }
      }
    }
  }

  // ---- msg1: A=ea, +node gather, gelu -> ms ----
  {
    const int n0 = w*32;
    f32x4 acc[4][2];
    #pragma unroll
    for (int mt=0;mt<4;++mt){
      #pragma unroll
      for (int nt=0;nt<2;++nt){ f32x4 z={0.f,0.f,0.f,0.f}; acc[mt][nt]=z; }
    }
    gemmK128<2>(eab, wpk+WOFF_WM1, n0, l15, lg, acc);
    #pragma unroll
    for (int nt=0;nt<2;++nt){
      int col = n0 + nt*16 + l15;
      float b = nb1[col];
      int cs = (1024 + col)*2;
      int ck = (1152 + col)*2;
      #pragma unroll
      for (int mt=0;mt<4;++mt){
        #pragma unroll
        for (int r=0;r<4;++r){
          int row = mt*16 + lg*4 + r;
          float g = bf2f(*(const u16*)(PnB + sof[row] + cs))
                  + bf2f(*(const u16*)(PnB + kof[row] + ck));
          float v = gelu_f(acc[mt][nt][r] + b + g);
          *(u16*)(msb + row*256 + ((col*2) ^ ((row&7)<<4))) = f2bf(v);
        }
      }
    }
  }
  __syncthreads();
  // ---- msg2: A=ms -> pp ----
  {
    const int n0 = w*32;
    f32x4 acc[4][2];
    #pragma unroll
    for (int mt=0;mt<4;++mt){
      #pragma unroll
      for (int nt=0;nt<2;++nt){ f32x4 z={0.f,0.f,0.f,0.f}; acc[mt][nt]=z; }
    }
    gemmK128<2>(msb, wpk+WOFF_NW2, n0, l15, lg, acc);
    #pragma unroll
    for (int nt=0;nt<2;++nt){
      int col = n0 + nt*16 + l15;
      float b = nb2[col];
      #pragma unroll
      for (int mt=0;mt<4;++mt){
        #pragma unroll
        for (int r=0;r<4;++r){
          int row = mt*16 + lg*4 + r;
          float v = gelu_f(acc[mt][nt][r] + b);
          *(u16*)(ppb + row*256 + ((col*2) ^ ((row&7)<<4))) = f2bf(v);
        }
      }
    }
  }
  __syncthreads();
  // ---- msg3: A=pp -> ms ----
  {
    const int n0 = w*32;
    f32x4 acc[4][2];
    #pragma unroll
    for (int mt=0;mt<4;++mt){
      #pragma unroll
      for (int nt=0;nt<2;++nt){ f32x4 z={0.f,0.f,0.f,0.f}; acc[mt][nt]=z; }
    }
    gemmK128<2>(ppb, wpk+WOFF_NW3, n0, l15, lg, acc);
    #pragma unroll
    for (int nt=0;nt<2;++nt){
      int col = n0 + nt*16 + l15;
      float b = nb3[col];
      #pragma unroll
      for (int mt=0;mt<4;++mt){
        #pragma unroll
        for (int r=0;r<4;++r){
          int row = mt*16 + lg*4 + r;
          float v = acc[mt][nt][r] + b;
          *(u16*)(msb + row*256 + ((col*2) ^ ((row&7)<<4))) = f2bf(v);
        }
      }
    }
  }
  __syncthreads();
  // coalesced copy ms -> global msg (bf16)
  {
    int row = t>>2, q = t&3;
    const int swz = (row&7)<<4;
    #pragma unroll
    for (int c=0;c<4;++c){
      int j = q*4 + c;
      int4 v = *(const int4*)(msb + row*256 + ((j*16) ^ swz));
      *(int4*)((char*)msg + (size_t)(e0+row)*256 + j*16) = v;
    }
  }
}

// ---------------- CSR build ----------------
__global__ __launch_bounds__(1024) void k_scan(const u32* __restrict__ cnt, int* __restrict__ rowp, int* __restrict__ fillp)
{
  __shared__ int wsum[16];
  __shared__ int carry;
  const int t = threadIdx.x;
  const int lane = t&63, wid = t>>6;
  if (t==0) carry = 0;
  __syncthreads();
  for (int base = 0; base < N_NODES; base += 1024){
    int idx = base + t;
    int v = (idx < N_NODES) ? (int)cnt[idx] : 0;
    int x = v;
    for (int o=1;o<64;o<<=1){ int y = __shfl_up(x,o); if (lane>=o) x += y; }
    if (lane==63) wsum[wid] = x;
    __syncthreads();
    if (wid==0){
      int wv = (lane<16)? wsum[lane] : 0;
      for (int o=1;o<16;o<<=1){ int y = __shfl_up(wv,o); if (lane>=o) wv += y; }
      if (lane<16) wsum[lane] = wv;
    }
    __syncthreads();
    int pre = (wid>0)? wsum[wid-1] : 0;
    int incl = carry + pre + x;
    if (idx < N_NODES){
      rowp[idx+1] = incl;
      fillp[idx] = incl - v;
      if (idx==0) rowp[0] = 0;
    }
    __syncthreads();
    if (t==1023) carry = incl;
    __syncthreads();
  }
}

__global__ __launch_bounds__(256) void k_scatter(const int* __restrict__ eidx, int* __restrict__ fillp, int* __restrict__ eids)
{
  int e = blockIdx.x*256 + threadIdx.x;
  if (e < N_EDGES){
    int sn = eidx[N_EDGES + e];
    int pos = atomicAdd(&fillp[sn], 1);
    eids[pos] = e;
  }
}

// ---------------- softmax denominators + per-edge-n attention ----------------
__global__ __launch_bounds__(256) void k_normsum(const int* __restrict__ eidx, const float* __restrict__ logits,
                                                 const u32* __restrict__ smax, float* __restrict__ norm)
{
  int e = blockIdx.x*256 + threadIdx.x;
  if (e < N_EDGES){
    int sn = eidx[N_EDGES + e];
    #pragma unroll
    for (int k=0;k<HEADS;++k){
      float m = fdec(smax[sn*HEADS+k]);
      atomicAdd(&norm[sn*HEADS+k], expf(logits[e*HEADS+k]-m));
    }
  }
}

__global__ __launch_bounds__(256) void k_attv(const int* __restrict__ eidx, const float* __restrict__ logits,
                                              const u32* __restrict__ smax, const float* __restrict__ norm,
                                              const u32* __restrict__ cnt, float* __restrict__ attv)
{
  int n = blockIdx.x*256 + threadIdx.x;
  if (n < N_NODES){
    int sn = eidx[N_EDGES + n];
    float c = 1e-12f * (float)cnt[sn];
    #pragma unroll
    for (int k=0;k<HEADS;++k){
      float m = fdec(smax[sn*HEADS+k]);
      attv[n*HEADS+k] = expf(logits[n*HEADS+k]-m) / (norm[sn*HEADS+k] + c);
    }
  }
}

// ---------------- per-node msg segment-sum (CSR, 4 waves/node) ----------------
__global__ __launch_bounds__(256) void k_msgsum(const u16* __restrict__ msg, const int* __restrict__ rowp,
                                                const int* __restrict__ eids, float* __restrict__ msgsum)
{
  __shared__ float red[3][128];
  const int n = blockIdx.x, t = threadIdx.x;
  const int w = t>>6, l = t&63;
  const int beg = rowp[n], end = rowp[n+1];
  float a0=0.f, a1=0.f;
  for (int i=beg+w; i<end; i+=4){
    int e = eids[i];
    u32 v = *(const u32*)(msg + (size_t)e*128 + l*2);
    a0 += __uint_as_float(v<<16);
    a1 += __uint_as_float(v & 0xFFFF0000u);
  }
  if (w>0){ red[w-1][l*2] = a0; red[w-1][l*2+1] = a1; }
  __syncthreads();
  if (w==0){
    #pragma unroll
    for (int j=0;j<3;++j){ a0 += red[j][l*2]; a1 += red[j][l*2+1]; }
    msgsum[(size_t)n*128 + l*2]   = a0;
    msgsum[(size_t)n*128 + l*2+1] = a1;
  }
}

// ---------------- node update: upd -> LN -> dense MLP -> LN ----------------
#define NB 16
__global__ __launch_bounds__(256) void k_node(
  const float* __restrict__ msgsum, const float* __restrict__ attv, const float* __restrict__ bb,
  const float* __restrict__ aggr_w, const float* __restrict__ aggr_b,
  const float* __restrict__ dw1, const float* __restrict__ db1,
  const float* __restrict__ dw2, const float* __restrict__ db2,
  const float* __restrict__ lng, const float* __restrict__ lnb,
  float* __restrict__ xout, u16* __restrict__ xbp)
{
  __shared__ float sms[NB][128];
  __shared__ float av[NB][4];
  __shared__ float updb[NB][132];
  __shared__ float xb[NB][132];
  __shared__ float dh[NB][512];
  const int t = threadIdx.x;
  const int nbase = blockIdx.x*NB;

  for (int f=t; f<NB*128; f+=256){ int nn=f>>7, d=f&127; sms[nn][d] = msgsum[(size_t)(nbase+nn)*128 + d]; }
  if (t < NB*4) av[t>>2][t&3] = attv[nbase*4 + t];
  __syncthreads();
  for (int f=t; f<NB*512; f+=256){ int nn=f>>9, j=f&511; dh[nn][j] = av[nn][j>>7]*sms[nn][j&127]; }
  __syncthreads();
  {
    const int i = t&127, half = t>>7;
    const float* wr = aggr_w + (size_t)i*512;
    float acc[8];
    #pragma unroll
    for (int u=0;u<8;++u) acc[u]=0.f;
    for (int jb=0;jb<512;jb+=8){
      float wreg[8];
      #pragma unroll
      for (int u=0;u<8;++u) wreg[u]=wr[jb+u];
      #pragma unroll
      for (int nn8=0;nn8<8;++nn8){
        float s=0.f;
        #pragma unroll
        for (int u=0;u<8;++u) s += dh[half*8+nn8][jb+u]*wreg[u];
        acc[nn8] += s;
      }
    }
    float ab = aggr_b[i];
    #pragma unroll
    for (int nn8=0;nn8<8;++nn8) updb[half*8+nn8][i] = acc[nn8] + ab;
  }
  __syncthreads();
  {
    const int nn = t>>4, sl = t&15;
    float vals[8]; float s=0.f, ss=0.f;
    #pragma unroll
    for (int c=0;c<8;++c){
      int col = sl + c*16;
      float v = bb[(size_t)(nbase+nn)*128 + col] + updb[nn][col];
      vals[c]=v; s+=v; ss+=v*v;
    }
    s += __shfl_xor(s,1); ss += __shfl_xor(ss,1);
    s += __shfl_xor(s,2); ss += __shfl_xor(ss,2);
    s += __shfl_xor(s,4); ss += __shfl_xor(ss,4);
    s += __shfl_xor(s,8); ss += __shfl_xor(ss,8);
    float mu = s*(1.f/128.f), var = ss*(1.f/128.f)-mu*mu, rstd = rsqrtf(var+1e-5f);
    #pragma unroll
    for (int c=0;c<8;++c){
      int col = sl + c*16;
      xb[nn][col] = (vals[c]-mu)*rstd*lng[col] + lnb[col];
    }
  }
  __syncthreads();
  for (int rep=0; rep<32; ++rep){
    int nn = rep>>1;
    int j = ((rep&1)<<8) + t;
    const float* wr = dw1 + (size_t)j*128;
    float s = 0.f;
    for (int d=0; d<128; ++d) s += xb[nn][d]*wr[d];
    dh[nn][j] = gelu_f(s + db1[j]);
  }
  __syncthreads();
  {
    const int i = t&127, half = t>>7;
    const float* wr = dw2 + (size_t)i*512;
    float acc[8];
    #pragma unroll
    for (int u=0;u<8;++u) acc[u]=0.f;
    for (int jb=0;jb<512;jb+=8){
      float wreg[8];
      #pragma unroll
      for (int u=0;u<8;++u) wreg[u]=wr[jb+u];
      #pragma unroll
      for (int nn8=0;nn8<8;++nn8){
        float s=0.f;
        #pragma unroll
        for (int u=0;u<8;++u) s += dh[half*8+nn8][jb+u]*wreg[u];
        acc[nn8]+=s;
      }
    }
    float b2 = db2[i];
    #pragma unroll
    for (int nn8=0;nn8<8;++nn8){
      int nn = half*8+nn8;
      xb[nn][i] = acc[nn8] + b2 + updb[nn][i];
    }
  }
  __syncthreads();
  {
    const int nn = t>>4, sl = t&15;
    float vals[8]; float s=0.f, ss=0.f;
    #pragma unroll
    for (int c=0;c<8;++c){
      int col = sl + c*16;
      float v = xb[nn][col];
      vals[c]=v; s+=v; ss+=v*v;
    }
    s += __shfl_xor(s,1); ss += __shfl_xor(ss,1);
    s += __shfl_xor(s,2); ss += __shfl_xor(ss,2);
    s += __shfl_xor(s,4); ss += __shfl_xor(ss,4);
    s += __shfl_xor(s,8); ss += __shfl_xor(ss,8);
    float mu = s*(1.f/128.f), var = ss*(1.f/128.f)-mu*mu, rstd = rsqrtf(var+1e-5f);
    #pragma unroll
    for (int c=0;c<8;++c){
      int col = sl + c*16;
      float o = (vals[c]-mu)*rstd*lng[col] + lnb[col];
      xout[(size_t)(nbase+nn)*128 + col] = o;
      xbp[(size_t)(nbase+nn)*128 + col] = f2bf(o);
    }
  }
}

// ---------------- edge pass C: edge-update MLP + LN -> eout ----------------
__global__ __launch_bounds__(256,3) void k_edgeC(
  const float* __restrict__ eattr, const int* __restrict__ eidx,
  const u16* __restrict__ wpk, const u16* __restrict__ Xp,
  const float* __restrict__ eb1, const float* __restrict__ eb2, const float* __restrict__ eb3,
  const float* __restrict__ lng, const float* __restrict__ lnb,
  float* __restrict__ eout)
{
  __shared__ u16 ea[64*128];
  __shared__ u16 ms[64*128];
  __shared__ u16 pp[64*128];
  __shared__ int sof[64], kof[64];
  __shared__ float reds[4][64], redss[4][64];
  __shared__ float mrs[64][2];
  char* eab=(char*)ea; char* msb=(char*)ms; char* ppb=(char*)pp;
  const char* XpB = (const char*)Xp;
  const int t = threadIdx.x;
  const int e0 = blockIdx.x*64;
  const int w = t>>6, l = t&63, l15 = l&15, lg = l>>4;
  const int n0 = w*32;

  stage_ea(eab, eattr, e0, t);
  if (t < 64){
    int s = eidx[e0+t], k = eidx[N_EDGES + e0 + t];
    sof[t] = s*512; kof[t] = k*512;   // byte offsets into Xp rows
  }
  __syncthreads();

  // e1: A=ea, +x gather, gelu -> ms
  {
    f32x4 acc[4][2];
    #pragma unroll
    for (int mt=0;mt<4;++mt){
      #pragma unroll
      for (int nt=0;nt<2;++nt){ f32x4 z={0.f,0.f,0.f,0.f}; acc[mt][nt]=z; }
    }
    gemmK128<2>(eab, wpk+WOFF_WE1, n0, l15, lg, acc);
    #pragma unroll
    for (int nt=0;nt<2;++nt){
      int col = n0 + nt*16 + l15;
      float b = eb1[col];
      int cs = col*2;
      int ck = (128 + col)*2;
      #pragma unroll
      for (int mt=0;mt<4;++mt){
        #pragma unroll
        for (int r=0;r<4;++r){
          int row = mt*16 + lg*4 + r;
          float g = bf2f(*(const u16*)(XpB + sof[row] + cs))
                  + bf2f(*(const u16*)(XpB + kof[row] + ck));
          float v = gelu_f(acc[mt][nt][r] + b + g);
          *(u16*)(msb + row*256 + ((col*2) ^ ((row&7)<<4))) = f2bf(v);
        }
      }
    }
  }
  __syncthreads();
  // e2: A=ms -> pp
  {
    f32x4 acc[4][2];
    #pragma unroll
    for (int mt=0;mt<4;++mt){
      #pragma unroll
      for (int nt=0;nt<2;++nt){ f32x4 z={0.f,0.f,0.f,0.f}; acc[mt][nt]=z; }
    }
    gemmK128<2>(msb, wpk+WOFF_EW2, n0, l15, lg, acc);
    #pragma unroll
    for (int nt=0;nt<2;++nt){
      int col = n0 + nt*16 + l15;
      float b = eb2[col];
      #pragma unroll
      for (int mt=0;mt<4;++mt){
        #pragma unroll
        for (int r=0;r<4;++r){
          int row = mt*16 + lg*4 + r;
          float v = gelu_f(acc[mt][nt][r] + b);
          *(u16*)(ppb + row*256 + ((col*2) ^ ((row&7)<<4))) = f2bf(v);
        }
      }
    }
  }
  __syncthreads();
  // e3: A=pp -> acc ; += eb3 + eattr ; cross-wave LN ; -> eout
  f32x4 acc[4][2];
  {
    #pragma unroll
    for (int mt=0;mt<4;++mt){
      #pragma unroll
      for (int nt=0;nt<2;++nt){ f32x4 z={0.f,0.f,0.f,0.f}; acc[mt][nt]=z; }
    }
    gemmK128<2>(ppb, wpk+WOFF_EW3, n0, l15, lg, acc);
    #pragma unroll
    for (int nt=0;nt<2;++nt){
      int col = n0 + nt*16 + l15;
      float b3 = eb3[col];
      #pragma unroll
      for (int mt=0;mt<4;++mt){
        #pragma unroll
        for (int r=0;r<4;++r){
          int row = mt*16 + lg*4 + r;
          float ev = bf2f(*(const u16*)(eab + row*256 + ((col*2) ^ ((row&7)<<4))));
          acc[mt][nt][r] += b3 + ev;
        }
      }
    }
    #pragma unroll
    for (int mt=0;mt<4;++mt){
      #pragma unroll
      for (int r=0;r<4;++r){
        float s  = acc[mt][0][r] + acc[mt][1][r];
        float ss = acc[mt][0][r]*acc[mt][0][r] + acc[mt][1][r]*acc[mt][1][r];
        s += __shfl_xor(s,1); ss += __shfl_xor(ss,1);
        s += __shfl_xor(s,2); ss += __shfl_xor(ss,2);
        s += __shfl_xor(s,4); ss += __shfl_xor(ss,4);
        s += __shfl_xor(s,8); ss += __shfl_xor(ss,8);
        if (l15==0){
          int row = mt*16 + lg*4 + r;
          reds[w][row] = s; redss[w][row] = ss;
        }
      }
    }
  }
  __syncthreads();
  if (t < 64){
    float s  = reds[0][t]+reds[1][t]+reds[2][t]+reds[3][t];
    float ss = redss[0][t]+redss[1][t]+redss[2][t]+redss[3][t];
    float mu = s*(1.f/128.f);
    float var = ss*(1.f/128.f) - mu*mu;
    mrs[t][0] = mu;
    mrs[t][1] = rsqrtf(var + 1e-5f);
  }
  __syncthreads();
  #pragma unroll
  for (int nt=0;nt<2;++nt){
    int col = n0 + nt*16 + l15;
    float g = lng[col], b = lnb[col];
    #pragma unroll
    for (int mt=0;mt<4;++mt){
      #pragma unroll
      for (int r=0;r<4;++r){
        int row = mt*16 + lg*4 + r;
        float o = (acc[mt][nt][r] - mrs[row][0])*mrs[row][1]*g + b;
        *(u16*)(msb + row*256 + ((col*2) ^ ((row&7)<<4))) = f2bf(o);
      }
    }
  }
  __syncthreads();
  {
    int row = t>>2, q = t&3;
    const int swz = (row&7)<<4;
    float* orow = eout + (size_t)(e0+row)*128;
    #pragma unroll
    for (int c=0;c<4;++c){
      int j = q*4+c;
      int4 v = *(const int4*)(msb + row*256 + ((j*16) ^ swz));
      u32 w0=(u32)v.x, w1=(u32)v.y, w2=(u32)v.z, w3=(u32)v.w;
      float4 f0, f1;
      f0.x = __uint_as_float(w0<<16); f0.y = __uint_as_float(w0 & 0xFFFF0000u);
      f0.z = __uint_as_float(w1<<16); f0.w = __uint_as_float(w1 & 0xFFFF0000u);
      f1.x = __uint_as_float(w2<<16); f1.y = __uint_as_float(w2 & 0xFFFF0000u);
      f1.z = __uint_as_float(w3<<16); f1.w = __uint_as_float(w3 & 0xFFFF0000u);
      ((float4*)orow)[j*2]   = f0;
      ((float4*)orow)[j*2+1] = f1;
    }
  }
}

// ---------------- launch ----------------
static inline size_t alup(size_t x){ return (x + 255) & ~(size_t)255; }

extern "C" void kernel_launch(void* const* d_in, const int* in_sizes, int n_in,
                              void* d_out, int out_size, void* d_ws, size_t ws_size,
                              hipStream_t stream)
{
  (void)in_sizes; (void)n_in; (void)out_size; (void)ws_size;
  const float* bb    = (const float*)d_in[0];
  const float* eattr = (const float*)d_in[1];
  const int*   eidx  = (const int*)d_in[2];
  const float* aW_w  = (const float*)d_in[3];
  const float* aW_b  = (const float*)d_in[4];
  const float* aA_w  = (const float*)d_in[5];
  const float* aA_b  = (const float*)d_in[6];
  const float* nw1   = (const float*)d_in[7];
  const float* nb1   = (const float*)d_in[8];
  const float* nw2   = (const float*)d_in[9];
  const float* nb2   = (const float*)d_in[10];
  const float* nw3   = (const float*)d_in[11];
  const float* nb3   = (const float*)d_in[12];
  const float* dw1   = (const float*)d_in[13];
  const float* db1   = (const float*)d_in[14];
  const float* dw2   = (const float*)d_in[15];
  const float* db2   = (const float*)d_in[16];
  const float* ew1   = (const float*)d_in[17];
  const float* eb1   = (const float*)d_in[18];
  const float* ew2   = (const float*)d_in[19];
  const float* eb2   = (const float*)d_in[20];
  const float* ew3   = (const float*)d_in[21];
  const float* eb3   = (const float*)d_in[22];
  const float* aggr_w= (const float*)d_in[23];
  const float* aggr_b= (const float*)d_in[24];
  const float* ln1g  = (const float*)d_in[25];
  const float* ln1b  = (const float*)d_in[26];
  const float* lneg  = (const float*)d_in[27];
  const float* lneb  = (const float*)d_in[28];

  char* p = (char*)d_ws;
  auto take = [&](size_t bytes)->char*{ char* r = p; p += alup(bytes); return r; };
  u16*   wpk    = (u16*)  take((size_t)WPACK2*2);
  u16*   bbp    = (u16*)  take((size_t)N_NODES*128*2);
  u16*   xbp    = (u16*)  take((size_t)N_NODES*128*2);
  u16*   Pn     = (u16*)  take((size_t)NPAD*1280*2);
  u16*   Xp     = (u16*)  take((size_t)NPAD*256*2);
  float* logits = (float*)take((size_t)N_EDGES*HEADS*4);
  u32*   smax   = (u32*)  take((size_t)N_NODES*HEADS*4);
  float* norm   = (float*)take((size_t)N_NODES*HEADS*4);
  u32*   cnt    = (u32*)  take((size_t)N_NODES*4);
  int*   rowp   = (int*)  take((size_t)(N_NODES+1)*4);
  int*   fillp  = (int*)  take((size_t)(N_NODES+1)*4);
  int*   eids   = (int*)  take((size_t)N_EDGES*4);
  float* attv   = (float*)take((size_t)N_NODES*HEADS*4);
  float* msgsum = (float*)take((size_t)N_NODES*128*4);

  float* xout = (float*)d_out;
  float* eout = xout + (size_t)N_NODES*128;
  u16*   msg  = (u16*)eout;   // msg bf16 scratch lives in eout region until k_edgeC

  k_pack   <<<dim3(10000), dim3(256), 0, stream>>>(aW_w,nw1,nw2,nw3,ew1,ew2,ew3,bb,wpk,bbp);
  k_init   <<<dim3(313),   dim3(256), 0, stream>>>(smax,norm,cnt);
  k_nproj  <<<dim3(313),   dim3(256), 0, stream>>>(bbp,wpk,Pn);
  k_edgeA  <<<dim3(9375),  dim3(256), 0, stream>>>(eattr,eidx,wpk,Pn,aW_b,aA_w,aA_b,nb1,nb2,nb3,logits,smax,cnt,msg);
  k_scan   <<<dim3(1),     dim3(1024),0, stream>>>(cnt,rowp,fillp);
  k_scatter<<<dim3(2344),  dim3(256), 0, stream>>>(eidx,fillp,eids);
  k_normsum<<<dim3(2344),  dim3(256), 0, stream>>>(eidx,logits,smax,norm);
  k_attv   <<<dim3(79),    dim3(256), 0, stream>>>(eidx,logits,smax,norm,cnt,attv);
  k_msgsum <<<dim3(20000), dim3(256), 0, stream>>>(msg,rowp,eids,msgsum);
  k_node   <<<dim3(1250),  dim3(256), 0, stream>>>(msgsum,attv,bb,aggr_w,aggr_b,dw1,db1,dw2,db2,ln1g,ln1b,xout,xbp);
  k_xproj  <<<dim3(313),   dim3(256), 0, stream>>>(xbp,wpk,Xp);
  k_edgeC  <<<dim3(9375),  dim3(256), 0, stream>>>(eattr,eidx,wpk,Xp,eb1,eb2,eb3,lneg,lneb,eout);
}

// Round 3
// 2366.682 us; speedup vs baseline: 2.0194x; 2.0194x over previous
//
#include <hip/hip_runtime.h>
#include <hip/hip_bf16.h>

#define N_NODES 20000
#define N_EDGES 600000
#define HEADS 4

// packed bf16 weight offsets (elements) — rows are K-major
#define WOFF_AW   0        // [4*128][384]
#define WOFF_NW1  196608   // [128][384]
#define WOFF_NW2  245760   // [128][128]
#define WOFF_NW3  262144   // [128][128]
#define WOFF_EW1  278528   // [128][384]
#define WOFF_EW2  327680   // [128][128]
#define WOFF_EW3  344064   // [128][128]
#define WPACK_TOT 360448

typedef __attribute__((ext_vector_type(8))) short s16x8;
typedef __attribute__((ext_vector_type(4))) float f32x4;
typedef unsigned int u32;
typedef unsigned short u16;

__device__ __forceinline__ float bf2f(u16 h){ return __uint_as_float(((u32)h)<<16); }
__device__ __forceinline__ u16 f2bf(float f){
  u32 u = __float_as_uint(f);
  u32 r = u + 0x7FFFu + ((u>>16)&1u);
  return (u16)(r>>16);
}
__device__ __forceinline__ float gelu_f(float x){ return 0.5f*x*(1.0f+erff(x*0.70710678118654752f)); }
__device__ __forceinline__ u32 fkey(float f){ u32 u = __float_as_uint(f); return (u & 0x80000000u) ? ~u : (u | 0x80000000u); }
__device__ __forceinline__ float fdec(u32 k){ return (k & 0x80000000u) ? __uint_as_float(k & 0x7FFFFFFFu) : __uint_as_float(~k); }

// ---------------- pack weights + bb to bf16 ----------------
__global__ __launch_bounds__(256) void k_pack(
    const float* __restrict__ aW, const float* __restrict__ nw1, const float* __restrict__ nw2,
    const float* __restrict__ nw3, const float* __restrict__ ew1, const float* __restrict__ ew2,
    const float* __restrict__ ew3, const float* __restrict__ bb,
    u16* __restrict__ wpk, u16* __restrict__ bbp)
{
  int i = blockIdx.x*256 + threadIdx.x;
  if (i < WPACK_TOT){
    float v;
    if      (i < WOFF_NW1) v = aW[i];
    else if (i < WOFF_NW2) v = nw1[i-WOFF_NW1];
    else if (i < WOFF_NW3) v = nw2[i-WOFF_NW2];
    else if (i < WOFF_EW1) v = nw3[i-WOFF_NW3];
    else if (i < WOFF_EW2) v = ew1[i-WOFF_EW1];
    else if (i < WOFF_EW3) v = ew2[i-WOFF_EW2];
    else                   v = ew3[i-WOFF_EW3];
    wpk[i] = f2bf(v);
  }
  if (i < N_NODES*128) bbp[i] = f2bf(bb[i]);
}

__global__ __launch_bounds__(256) void k_init(u32* __restrict__ smax, float* __restrict__ norm, u32* __restrict__ cnt)
{
  int i = blockIdx.x*256 + threadIdx.x;
  if (i < N_NODES*HEADS){ smax[i] = 0x007FFFFFu; norm[i] = 0.f; }
  if (i < N_NODES) cnt[i] = 0u;
}

// ---------------- strided GEMM helper (A tile in LDS, swizzled rows) ----------------
// A rows: byte = row*RS + ((chunk*16) ^ ((l15&7)<<4)), chunk = ks*4+lg
// B rows: wb[(n0+nt*16+l15)*KROW + ks*32 + lg*8]
template<int NT, int KS, int RS, int KROW>
__device__ __forceinline__ void gemmT(const char* ab, const u16* __restrict__ wb,
                                      int n0, int l15, int lg, f32x4 (&acc)[4][NT])
{
  const int swz = (l15&7)<<4;
  for (int ks=0; ks<KS; ++ks){
    s16x8 af[4];
    #pragma unroll
    for (int mt=0;mt<4;++mt)
      af[mt] = *(const s16x8*)(ab + (mt*16+l15)*RS + (((ks*4+lg)*16) ^ swz));
    #pragma unroll
    for (int nt=0;nt<NT;++nt){
      s16x8 bf = *(const s16x8*)(wb + (size_t)(n0+nt*16+l15)*KROW + ks*32 + lg*8);
      #pragma unroll
      for (int mt=0;mt<4;++mt)
        acc[mt][nt] = __builtin_amdgcn_mfma_f32_16x16x32_bf16(af[mt], bf, acc[mt][nt], 0,0,0);
    }
  }
}

template<int ACT, int RS>
__device__ __forceinline__ void store1(char* bp, int n0, int l15, int lg,
                                       f32x4 (&acc)[4][1], const float* __restrict__ bias)
{
  int col = n0 + l15;
  float b = bias[col];
  #pragma unroll
  for (int mt=0;mt<4;++mt){
    #pragma unroll
    for (int r=0;r<4;++r){
      int row = mt*16 + lg*4 + r;
      float v = acc[mt][0][r] + b;
      if (ACT) v = gelu_f(v);
      *(u16*)(bp + row*RS + ((col*2) ^ ((row&7)<<4))) = f2bf(v);
    }
  }
}

// stage h = [bb[src] | bb[snk] | eattr] into hs (row stride 768B, XOR-swizzled 16B chunks)
// 512 threads: 8 threads per edge row
__device__ __forceinline__ void stage512(char* hsb, const u16* __restrict__ ntab,
                                         const float* __restrict__ eattr, const int* __restrict__ eidx,
                                         int e0, int t)
{
  const int row = t>>3, p = t&7, ge = e0+row;
  const int swz = (row&7)<<4;
  char* rp = hsb + row*768;
  if (p < 4){
    int nid = eidx[(p<2 ? 0 : N_EDGES) + ge];
    const int4* src = (const int4*)(ntab + (size_t)nid*128 + (p&1)*64);
    int cb = p*8;
    #pragma unroll
    for (int c=0;c<8;++c){
      int4 v = src[c];
      *(int4*)(rp + (((cb+c)*16) ^ swz)) = v;
    }
  } else {
    int q = p-4;
    const float* er = eattr + (size_t)ge*128 + q*32;
    int cb = 32 + q*4;
    #pragma unroll
    for (int c=0;c<4;++c){
      float4 x0 = ((const float4*)er)[c*2];
      float4 x1 = ((const float4*)er)[c*2+1];
      int4 v;
      v.x = (int)((u32)f2bf(x0.x) | ((u32)f2bf(x0.y)<<16));
      v.y = (int)((u32)f2bf(x0.z) | ((u32)f2bf(x0.w)<<16));
      v.z = (int)((u32)f2bf(x1.x) | ((u32)f2bf(x1.y)<<16));
      v.w = (int)((u32)f2bf(x1.z) | ((u32)f2bf(x1.w)<<16));
      *(int4*)(rp + (((cb+c)*16) ^ swz)) = v;
    }
  }
}

// ---------------- edge pass A: logits + segment-max + msg MLP ----------------
__global__ __launch_bounds__(512,4) void k_edgeA(
  const u16* __restrict__ bbp, const float* __restrict__ eattr, const int* __restrict__ eidx,
  const u16* __restrict__ wpk,
  const float* __restrict__ aW_b, const float* __restrict__ aA_w, const float* __restrict__ aA_b,
  const float* __restrict__ nb1, const float* __restrict__ nb2, const float* __restrict__ nb3,
  float* __restrict__ logits, u32* __restrict__ smax, u32* __restrict__ cnt,
  u16* __restrict__ msg)
{
  __shared__ u16 hs[64*384];   // 48 KB, row stride 768 B
  __shared__ u16 ms[64*128];   // 16 KB, row stride 256 B
  char* hsb = (char*)hs; char* msb = (char*)ms;
  const int t = threadIdx.x;
  const int e0 = blockIdx.x*64;
  const int w = t>>6, l = t&63, l15 = l&15, lg = l>>4;

  stage512(hsb, bbp, eattr, eidx, e0, t);
  __syncthreads();

  // ---- P1a: logits. wave w -> head (w>>1), column half (w&1). 192 MFMA/wave ----
  {
    const u16* wh = wpk + WOFF_AW + (size_t)(w>>1)*(128*384);
    float lp[4][4];
    #pragma unroll
    for (int a=0;a<4;++a){
      #pragma unroll
      for (int b=0;b<4;++b) lp[a][b]=0.f;
    }
    #pragma unroll
    for (int ch=0; ch<2; ++ch){
      int n0 = (w&1)*64 + ch*32;
      f32x4 acc[4][2];
      #pragma unroll
      for (int mt=0;mt<4;++mt){
        #pragma unroll
        for (int nt=0;nt<2;++nt){ f32x4 z={0.f,0.f,0.f,0.f}; acc[mt][nt]=z; }
      }
      gemmT<2,12,768,384>(hsb, wh, n0, l15, lg, acc);
      #pragma unroll
      for (int nt=0;nt<2;++nt){
        int col = n0 + nt*16 + l15;
        int gcol = (w>>1)*128 + col;
        float bia = aW_b[gcol];
        float avw = aA_w[gcol];
        #pragma unroll
        for (int mt=0;mt<4;++mt){
          #pragma unroll
          for (int r=0;r<4;++r){
            float T = acc[mt][nt][r] + bia;
            T = (T>0.f) ? T : 0.2f*T;
            lp[mt][r] += T*avw;
          }
        }
      }
    }
    // reduce over the 16 lanes sharing lg; write wave partials into ms scratch
    float* lpart = (float*)msb;   // [8][64] floats, 2 KB
    #pragma unroll
    for (int mt=0;mt<4;++mt){
      #pragma unroll
      for (int r=0;r<4;++r){
        float v = lp[mt][r];
        v += __shfl_xor(v,1);
        v += __shfl_xor(v,2);
        v += __shfl_xor(v,4);
        v += __shfl_xor(v,8);
        if (l15==0) lpart[w*64 + mt*16 + lg*4 + r] = v;
      }
    }
  }
  __syncthreads();
  // ---- finalize logits: 256 threads cover 64 rows x 4 heads ----
  if (t < 256){
    const float* lpart = (const float*)msb;
    int row = t>>2, h = t&3;
    float s = lpart[(2*h)*64 + row] + lpart[(2*h+1)*64 + row] + aA_b[h];
    int e = e0 + row;
    logits[e*HEADS + h] = s;
    int sn = eidx[N_EDGES + e];
    atomicMax(&smax[sn*HEADS + h], fkey(s));
    if (h==0) atomicAdd(&cnt[sn], 1u);
  }
  __syncthreads();
  // ---- P1b: msg1 = gelu(h @ nw1^T + nb1) -> ms. 16 cols/wave ----
  {
    f32x4 acc[4][1];
    #pragma unroll
    for (int mt=0;mt<4;++mt){ f32x4 z={0.f,0.f,0.f,0.f}; acc[mt][0]=z; }
    gemmT<1,12,768,384>(hsb, wpk+WOFF_NW1, w*16, l15, lg, acc);
    store1<1,256>(msb, w*16, l15, lg, acc, nb1);
  }
  __syncthreads();
  // ---- P2: msg2 = gelu(ms @ nw2^T + nb2) -> pp (overlay: first 256B of each hs row) ----
  {
    f32x4 acc[4][1];
    #pragma unroll
    for (int mt=0;mt<4;++mt){ f32x4 z={0.f,0.f,0.f,0.f}; acc[mt][0]=z; }
    gemmT<1,4,256,128>(msb, wpk+WOFF_NW2, w*16, l15, lg, acc);
    store1<1,768>(hsb, w*16, l15, lg, acc, nb2);
  }
  __syncthreads();
  // ---- P3: msg3 = pp @ nw3^T + nb3 -> ms ----
  {
    f32x4 acc[4][1];
    #pragma unroll
    for (int mt=0;mt<4;++mt){ f32x4 z={0.f,0.f,0.f,0.f}; acc[mt][0]=z; }
    gemmT<1,4,768,128>(hsb, wpk+WOFF_NW3, w*16, l15, lg, acc);
    store1<0,256>(msb, w*16, l15, lg, acc, nb3);
  }
  __syncthreads();
  // ---- copy ms -> global msg (bf16), coalesced ----
  {
    int row = t>>3, p = t&7;
    const int swz = (row&7)<<4;
    #pragma unroll
    for (int c=0;c<2;++c){
      int j = p*2 + c;
      int4 v = *(const int4*)(msb + row*256 + ((j*16) ^ swz));
      *(int4*)((char*)msg + (size_t)(e0+row)*256 + j*16) = v;
    }
  }
}

// ---------------- CSR build ----------------
__global__ __launch_bounds__(1024) void k_scan(const u32* __restrict__ cnt, int* __restrict__ rowp, int* __restrict__ fillp)
{
  __shared__ int wsum[16];
  __shared__ int carry;
  const int t = threadIdx.x;
  const int lane = t&63, wid = t>>6;
  if (t==0) carry = 0;
  __syncthreads();
  for (int base = 0; base < N_NODES; base += 1024){
    int idx = base + t;
    int v = (idx < N_NODES) ? (int)cnt[idx] : 0;
    int x = v;
    for (int o=1;o<64;o<<=1){ int y = __shfl_up(x,o); if (lane>=o) x += y; }
    if (lane==63) wsum[wid] = x;
    __syncthreads();
    if (wid==0){
      int wv = (lane<16)? wsum[lane] : 0;
      for (int o=1;o<16;o<<=1){ int y = __shfl_up(wv,o); if (lane>=o) wv += y; }
      if (lane<16) wsum[lane] = wv;
    }
    __syncthreads();
    int pre = (wid>0)? wsum[wid-1] : 0;
    int incl = carry + pre + x;
    if (idx < N_NODES){
      rowp[idx+1] = incl;
      fillp[idx] = incl - v;
      if (idx==0) rowp[0] = 0;
    }
    __syncthreads();
    if (t==1023) carry = incl;
    __syncthreads();
  }
}

__global__ __launch_bounds__(256) void k_scatter(const int* __restrict__ eidx, int* __restrict__ fillp, int* __restrict__ eids)
{
  int e = blockIdx.x*256 + threadIdx.x;
  if (e < N_EDGES){
    int sn = eidx[N_EDGES + e];
    int pos = atomicAdd(&fillp[sn], 1);
    eids[pos] = e;
  }
}

// ---------------- softmax denominators + per-edge-n attention ----------------
__global__ __launch_bounds__(256) void k_normsum(const int* __restrict__ eidx, const float* __restrict__ logits,
                                                 const u32* __restrict__ smax, float* __restrict__ norm)
{
  int e = blockIdx.x*256 + threadIdx.x;
  if (e < N_EDGES){
    int sn = eidx[N_EDGES + e];
    #pragma unroll
    for (int k=0;k<HEADS;++k){
      float m = fdec(smax[sn*HEADS+k]);
      atomicAdd(&norm[sn*HEADS+k], expf(logits[e*HEADS+k]-m));
    }
  }
}

__global__ __launch_bounds__(256) void k_attv(const int* __restrict__ eidx, const float* __restrict__ logits,
                                              const u32* __restrict__ smax, const float* __restrict__ norm,
                                              const u32* __restrict__ cnt, float* __restrict__ attv)
{
  int n = blockIdx.x*256 + threadIdx.x;
  if (n < N_NODES){
    int sn = eidx[N_EDGES + n];
    float c = 1e-12f * (float)cnt[sn];
    #pragma unroll
    for (int k=0;k<HEADS;++k){
      float m = fdec(smax[sn*HEADS+k]);
      attv[n*HEADS+k] = expf(logits[n*HEADS+k]-m) / (norm[sn*HEADS+k] + c);
    }
  }
}

// ---------------- per-node msg segment-sum (CSR, 4 waves/node) ----------------
__global__ __launch_bounds__(256) void k_msgsum(const u16* __restrict__ msg, const int* __restrict__ rowp,
                                                const int* __restrict__ eids, float* __restrict__ msgsum)
{
  __shared__ float red[3][128];
  const int n = blockIdx.x, t = threadIdx.x;
  const int w = t>>6, l = t&63;
  const int beg = rowp[n], end = rowp[n+1];
  float a0=0.f, a1=0.f;
  for (int i=beg+w; i<end; i+=4){
    int e = eids[i];
    u32 v = *(const u32*)(msg + (size_t)e*128 + l*2);
    a0 += __uint_as_float(v<<16);
    a1 += __uint_as_float(v & 0xFFFF0000u);
  }
  if (w>0){ red[w-1][l*2] = a0; red[w-1][l*2+1] = a1; }
  __syncthreads();
  if (w==0){
    #pragma unroll
    for (int j=0;j<3;++j){ a0 += red[j][l*2]; a1 += red[j][l*2+1]; }
    msgsum[(size_t)n*128 + l*2]   = a0;
    msgsum[(size_t)n*128 + l*2+1] = a1;
  }
}

// ---------------- node update: upd -> LN -> dense MLP -> LN ----------------
#define NB 16
__global__ __launch_bounds__(256) void k_node(
  const float* __restrict__ msgsum, const float* __restrict__ attv, const float* __restrict__ bb,
  const float* __restrict__ aggr_w, const float* __restrict__ aggr_b,
  const float* __restrict__ dw1, const float* __restrict__ db1,
  const float* __restrict__ dw2, const float* __restrict__ db2,
  const float* __restrict__ lng, const float* __restrict__ lnb,
  float* __restrict__ xout, u16* __restrict__ xbp)
{
  __shared__ float sms[NB][128];
  __shared__ float av[NB][4];
  __shared__ float updb[NB][132];
  __shared__ float xb[NB][132];
  __shared__ float dh[NB][512];
  const int t = threadIdx.x;
  const int nbase = blockIdx.x*NB;

  for (int f=t; f<NB*128; f+=256){ int nn=f>>7, d=f&127; sms[nn][d] = msgsum[(size_t)(nbase+nn)*128 + d]; }
  if (t < NB*4) av[t>>2][t&3] = attv[nbase*4 + t];
  __syncthreads();
  for (int f=t; f<NB*512; f+=256){ int nn=f>>9, j=f&511; dh[nn][j] = av[nn][j>>7]*sms[nn][j&127]; }
  __syncthreads();
  {
    const int i = t&127, half = t>>7;
    const float* wr = aggr_w + (size_t)i*512;
    float acc[8];
    #pragma unroll
    for (int u=0;u<8;++u) acc[u]=0.f;
    for (int jb=0;jb<512;jb+=8){
      float wreg[8];
      #pragma unroll
      for (int u=0;u<8;++u) wreg[u]=wr[jb+u];
      #pragma unroll
      for (int nn8=0;nn8<8;++nn8){
        float s=0.f;
        #pragma unroll
        for (int u=0;u<8;++u) s += dh[half*8+nn8][jb+u]*wreg[u];
        acc[nn8] += s;
      }
    }
    float ab = aggr_b[i];
    #pragma unroll
    for (int nn8=0;nn8<8;++nn8) updb[half*8+nn8][i] = acc[nn8] + ab;
  }
  __syncthreads();
  {
    const int nn = t>>4, sl = t&15;
    float vals[8]; float s=0.f, ss=0.f;
    #pragma unroll
    for (int c=0;c<8;++c){
      int col = sl + c*16;
      float v = bb[(size_t)(nbase+nn)*128 + col] + updb[nn][col];
      vals[c]=v; s+=v; ss+=v*v;
    }
    s += __shfl_xor(s,1); ss += __shfl_xor(ss,1);
    s += __shfl_xor(s,2); ss += __shfl_xor(ss,2);
    s += __shfl_xor(s,4); ss += __shfl_xor(ss,4);
    s += __shfl_xor(s,8); ss += __shfl_xor(ss,8);
    float mu = s*(1.f/128.f), var = ss*(1.f/128.f)-mu*mu, rstd = rsqrtf(var+1e-5f);
    #pragma unroll
    for (int c=0;c<8;++c){
      int col = sl + c*16;
      xb[nn][col] = (vals[c]-mu)*rstd*lng[col] + lnb[col];
    }
  }
  __syncthreads();
  for (int rep=0; rep<32; ++rep){
    int nn = rep>>1;
    int j = ((rep&1)<<8) + t;
    const float* wr = dw1 + (size_t)j*128;
    float s = 0.f;
    for (int d=0; d<128; ++d) s += xb[nn][d]*wr[d];
    dh[nn][j] = gelu_f(s + db1[j]);
  }
  __syncthreads();
  {
    const int i = t&127, half = t>>7;
    const float* wr = dw2 + (size_t)i*512;
    float acc[8];
    #pragma unroll
    for (int u=0;u<8;++u) acc[u]=0.f;
    for (int jb=0;jb<512;jb+=8){
      float wreg[8];
      #pragma unroll
      for (int u=0;u<8;++u) wreg[u]=wr[jb+u];
      #pragma unroll
      for (int nn8=0;nn8<8;++nn8){
        float s=0.f;
        #pragma unroll
        for (int u=0;u<8;++u) s += dh[half*8+nn8][jb+u]*wreg[u];
        acc[nn8]+=s;
      }
    }
    float b2 = db2[i];
    #pragma unroll
    for (int nn8=0;nn8<8;++nn8){
      int nn = half*8+nn8;
      xb[nn][i] = acc[nn8] + b2 + updb[nn][i];
    }
  }
  __syncthreads();
  {
    const int nn = t>>4, sl = t&15;
    float vals[8]; float s=0.f, ss=0.f;
    #pragma unroll
    for (int c=0;c<8;++c){
      int col = sl + c*16;
      float v = xb[nn][col];
      vals[c]=v; s+=v; ss+=v*v;
    }
    s += __shfl_xor(s,1); ss += __shfl_xor(ss,1);
    s += __shfl_xor(s,2); ss += __shfl_xor(ss,2);
    s += __shfl_xor(s,4); ss += __shfl_xor(ss,4);
    s += __shfl_xor(s,8); ss += __shfl_xor(ss,8);
    float mu = s*(1.f/128.f), var = ss*(1.f/128.f)-mu*mu, rstd = rsqrtf(var+1e-5f);
    #pragma unroll
    for (int c=0;c<8;++c){
      int col = sl + c*16;
      float o = (vals[c]-mu)*rstd*lng[col] + lnb[col];
      xout[(size_t)(nbase+nn)*128 + col] = o;
      xbp[(size_t)(nbase+nn)*128 + col] = f2bf(o);
    }
  }
}

// ---------------- edge pass C: edge-update MLP + LN -> eout ----------------
__global__ __launch_bounds__(512,4) void k_edgeC(
  const u16* __restrict__ xbp, const float* __restrict__ eattr, const int* __restrict__ eidx,
  const u16* __restrict__ wpk,
  const float* __restrict__ eb1, const float* __restrict__ eb2, const float* __restrict__ eb3,
  const float* __restrict__ lng, const float* __restrict__ lnb,
  float* __restrict__ eout)
{
  __shared__ u16 hs[64*384];   // 48 KB
  __shared__ u16 ms[64*128];   // 16 KB
  char* hsb=(char*)hs; char* msb=(char*)ms;
  const int t = threadIdx.x;
  const int e0 = blockIdx.x*64;
  const int w = t>>6, l = t&63, l15 = l&15, lg = l>>4;
  const int n0 = w*16;

  stage512(hsb, xbp, eattr, eidx, e0, t);
  __syncthreads();

  // E1: gelu(h @ ew1^T + eb1) -> ms
  {
    f32x4 acc[4][1];
    #pragma unroll
    for (int mt=0;mt<4;++mt){ f32x4 z={0.f,0.f,0.f,0.f}; acc[mt][0]=z; }
    gemmT<1,12,768,384>(hsb, wpk+WOFF_EW1, n0, l15, lg, acc);
    store1<1,256>(msb, n0, l15, lg, acc, eb1);
  }
  __syncthreads();
  // E2: gelu(ms @ ew2^T + eb2) -> pp (hs overlay)
  {
    f32x4 acc[4][1];
    #pragma unroll
    for (int mt=0;mt<4;++mt){ f32x4 z={0.f,0.f,0.f,0.f}; acc[mt][0]=z; }
    gemmT<1,4,256,128>(msb, wpk+WOFF_EW2, n0, l15, lg, acc);
    store1<1,768>(hsb, n0, l15, lg, acc, eb2);
  }
  __syncthreads();
  // E3: pp @ ew3^T + eb3 + eattr ; LN across 128 cols ; write eout
  {
    f32x4 acc[4][1];
    #pragma unroll
    for (int mt=0;mt<4;++mt){ f32x4 z={0.f,0.f,0.f,0.f}; acc[mt][0]=z; }
    gemmT<1,4,768,128>(hsb, wpk+WOFF_EW3, n0, l15, lg, acc);
    int col = n0 + l15;
    float b3 = eb3[col];
    float v[4][4];
    float s=0.f, ss=0.f;
    #pragma unroll
    for (int mt=0;mt<4;++mt){
      #pragma unroll
      for (int r=0;r<4;++r){
        int row = mt*16 + lg*4 + r;
        float ea = bf2f(*(const u16*)(hsb + row*768 + ((512 + col*2) ^ ((row&7)<<4))));
        float x = acc[mt][0][r] + b3 + ea;
        v[mt][r] = x;
      }
    }
    // per-row partial sums over this wave's 16 cols
    float* wp = (float*)msb;        // [8][64] s then [8][64] ss (4 KB); ms dead now
    #pragma unroll
    for (int mt=0;mt<4;++mt){
      #pragma unroll
      for (int r=0;r<4;++r){
        float a = v[mt][r], b = v[mt][r]*v[mt][r];
        a += __shfl_xor(a,1); b += __shfl_xor(b,1);
        a += __shfl_xor(a,2); b += __shfl_xor(b,2);
        a += __shfl_xor(a,4); b += __shfl_xor(b,4);
        a += __shfl_xor(a,8); b += __shfl_xor(b,8);
        if (l15==0){
          int row = mt*16 + lg*4 + r;
          wp[w*64 + row] = a;
          wp[512 + w*64 + row] = b;
        }
      }
    }
    __syncthreads();
    float* mrs = (float*)(msb + 4096);  // [2][64]
    if (t < 64){
      const float* q = (const float*)msb;
      float a=0.f, b=0.f;
      #pragma unroll
      for (int j=0;j<8;++j){ a += q[j*64+t]; b += q[512+j*64+t]; }
      float mu = a*(1.f/128.f);
      float var = b*(1.f/128.f) - mu*mu;
      mrs[t] = mu;
      mrs[64+t] = rsqrtf(var + 1e-5f);
    }
    __syncthreads();
    float g = lng[col], bb_ = lnb[col];
    #pragma unroll
    for (int mt=0;mt<4;++mt){
      #pragma unroll
      for (int r=0;r<4;++r){
        int row = mt*16 + lg*4 + r;
        float o = (v[mt][r] - mrs[row])*mrs[64+row]*g + bb_;
        eout[(size_t)(e0+row)*128 + col] = o;
      }
    }
  }
}

// ---------------- launch ----------------
static inline size_t alup(size_t x){ return (x + 255) & ~(size_t)255; }

extern "C" void kernel_launch(void* const* d_in, const int* in_sizes, int n_in,
                              void* d_out, int out_size, void* d_ws, size_t ws_size,
                              hipStream_t stream)
{
  (void)in_sizes; (void)n_in; (void)out_size; (void)ws_size;
  const float* bb    = (const float*)d_in[0];
  const float* eattr = (const float*)d_in[1];
  const int*   eidx  = (const int*)d_in[2];
  const float* aW_w  = (const float*)d_in[3];
  const float* aW_b  = (const float*)d_in[4];
  const float* aA_w  = (const float*)d_in[5];
  const float* aA_b  = (const float*)d_in[6];
  const float* nw1   = (const float*)d_in[7];
  const float* nb1   = (const float*)d_in[8];
  const float* nw2   = (const float*)d_in[9];
  const float* nb2   = (const float*)d_in[10];
  const float* nw3   = (const float*)d_in[11];
  const float* nb3   = (const float*)d_in[12];
  const float* dw1   = (const float*)d_in[13];
  const float* db1   = (const float*)d_in[14];
  const float* dw2   = (const float*)d_in[15];
  const float* db2   = (const float*)d_in[16];
  const float* ew1   = (const float*)d_in[17];
  const float* eb1   = (const float*)d_in[18];
  const float* ew2   = (const float*)d_in[19];
  const float* eb2   = (const float*)d_in[20];
  const float* ew3   = (const float*)d_in[21];
  const float* eb3   = (const float*)d_in[22];
  const float* aggr_w= (const float*)d_in[23];
  const float* aggr_b= (const float*)d_in[24];
  const float* ln1g  = (const float*)d_in[25];
  const float* ln1b  = (const float*)d_in[26];
  const float* lneg  = (const float*)d_in[27];
  const float* lneb  = (const float*)d_in[28];

  char* p = (char*)d_ws;
  auto take = [&](size_t bytes)->char*{ char* r = p; p += alup(bytes); return r; };
  u16*   wpk    = (u16*)  take((size_t)WPACK_TOT*2);
  u16*   bbp    = (u16*)  take((size_t)N_NODES*128*2);
  u16*   xbp    = (u16*)  take((size_t)N_NODES*128*2);
  float* logits = (float*)take((size_t)N_EDGES*HEADS*4);
  u32*   smax   = (u32*)  take((size_t)N_NODES*HEADS*4);
  float* norm   = (float*)take((size_t)N_NODES*HEADS*4);
  u32*   cnt    = (u32*)  take((size_t)N_NODES*4);
  int*   rowp   = (int*)  take((size_t)(N_NODES+1)*4);
  int*   fillp  = (int*)  take((size_t)(N_NODES+1)*4);
  int*   eids   = (int*)  take((size_t)N_EDGES*4);
  float* attv   = (float*)take((size_t)N_NODES*HEADS*4);
  float* msgsum = (float*)take((size_t)N_NODES*128*4);

  float* xout = (float*)d_out;
  float* eout = xout + (size_t)N_NODES*128;
  u16*   msg  = (u16*)eout;   // msg bf16 scratch lives in eout region until k_edgeC

  k_pack   <<<dim3(10000), dim3(256), 0, stream>>>(aW_w,nw1,nw2,nw3,ew1,ew2,ew3,bb,wpk,bbp);
  k_init   <<<dim3(313),   dim3(256), 0, stream>>>(smax,norm,cnt);
  k_edgeA  <<<dim3(9375),  dim3(512), 0, stream>>>(bbp,eattr,eidx,wpk,aW_b,aA_w,aA_b,nb1,nb2,nb3,logits,smax,cnt,msg);
  k_scan   <<<dim3(1),     dim3(1024),0, stream>>>(cnt,rowp,fillp);
  k_scatter<<<dim3(2344),  dim3(256), 0, stream>>>(eidx,fillp,eids);
  k_normsum<<<dim3(2344),  dim3(256), 0, stream>>>(eidx,logits,smax,norm);
  k_attv   <<<dim3(79),    dim3(256), 0, stream>>>(eidx,logits,smax,norm,cnt,attv);
  k_msgsum <<<dim3(20000), dim3(256), 0, stream>>>(msg,rowp,eids,msgsum);
  k_node   <<<dim3(1250),  dim3(256), 0, stream>>>(msgsum,attv,bb,aggr_w,aggr_b,dw1,db1,dw2,db2,ln1g,ln1b,xout,xbp);
  k_edgeC  <<<dim3(9375),  dim3(512), 0, stream>>>(xbp,eattr,eidx,wpk,eb1,eb2,eb3,lneg,lneb,eout);
}